// Round 7
// baseline (304.237 us; speedup 1.0000x reference)
//
#include <hip/hip_runtime.h>
#include <hip/hip_bf16.h>

typedef __attribute__((ext_vector_type(8))) short short8;
typedef __attribute__((ext_vector_type(4))) float floatx4;

#define N_ROWS 32768
#define D_DIM  128
#define H_KEYS 8192
#define C_COLS 100
#define BM     64
#define BH     128
#define P_STRIDE  136   // ushorts per P row (272 B, 16B-aligned rows)
#define P_BYTES   (BM * P_STRIDE * 2)   // 17408 B per buffer
#define OL_STRIDE 113   // floats per OL row (odd -> conflict-free epilogue)
#define LOG2E 1.4426950408889634f

__device__ __forceinline__ unsigned short f2bf(float f) {
  union { float f; unsigned int u; } v; v.f = f;
  unsigned int r = v.u + 0x7fffu + ((v.u >> 16) & 1u);  // RNE
  return (unsigned short)(r >> 16);
}

// v_cvt_pk_bf16_f32: two fp32 -> packed bf16 (a in low 16, b in high 16)
__device__ __forceinline__ unsigned int pk2bf(float a, float b) {
  union { __hip_bfloat162 h; unsigned int u; } c;
  c.h = __float22bfloat162_rn(float2{a, b});
  return c.u;
}

// ---------------------------------------------------------------------------
// pack_all: single-launch fusion of the three preprocessing passes
// (verbatim round-0 logic, harness-verified twice).
//   blocks [0,512):    pack_k — K fp32 -> MFMA A-frag order, scaled 2*log2e/T
//   blocks [512,768):  pack_v — V -> PV B-frag order, 112 cols, ones at 100
//   blocks [768,2816): ksq    — ksq[h] = -|k_h|^2 * log2e / T (1 wave/key)
// ---------------------------------------------------------------------------
__global__ __launch_bounds__(256) void pack_all(const float* __restrict__ keys,
                                                const float* __restrict__ values,
                                                const float* __restrict__ temp,
                                                unsigned short* __restrict__ kp,
                                                unsigned short* __restrict__ vp,
                                                float* __restrict__ ksq) {
  const int bid = blockIdx.x;
  if (bid < 512) {
    int gid = bid * 256 + threadIdx.x;
    int lane = gid & 63;
    int c = (gid >> 6) & 3;
    int rt = gid >> 8;
    float scale = 2.0f * LOG2E / temp[0];
    int row = rt * 16 + (lane & 15);
    int d0 = c * 32 + (lane >> 4) * 8;
    const float* s = keys + (size_t)row * D_DIM + d0;
    short8 o;
#pragma unroll
    for (int j = 0; j < 8; ++j) o[j] = (short)f2bf(s[j] * scale);
    *(short8*)(kp + (size_t)gid * 8) = o;
  } else if (bid < 768) {
    __shared__ float vt[32 * 113];
    int g = bid - 512;
    int tid = threadIdx.x;
    for (int idx = tid; idx < 32 * 112; idx += 256) {
      int k = idx / 112, col = idx - k * 112;
      float val;
      if (col < C_COLS) val = values[(size_t)(g * 32 + k) * C_COLS + col];
      else val = (col == C_COLS) ? 1.0f : 0.0f;
      vt[k * 113 + col] = val;
    }
    __syncthreads();
    for (int u = tid; u < 7 * 64; u += 256) {
      int ct = u >> 6, l = u & 63;
      int n0 = l & 15, q = l >> 4;
      short8 o;
#pragma unroll
      for (int j = 0; j < 8; ++j) o[j] = (short)f2bf(vt[(q * 8 + j) * 113 + ct * 16 + n0]);
      *(short8*)(vp + ((size_t)(g * 7 + ct) * 64 + l) * 8) = o;
    }
  } else {
    int wid = ((bid - 768) * 256 + threadIdx.x) >> 6;  // key index
    int lane = threadIdx.x & 63;
    const float2* row = (const float2*)(keys + (size_t)wid * D_DIM);
    float2 v = row[lane];
    float s = v.x * v.x + v.y * v.y;
#pragma unroll
    for (int off = 32; off > 0; off >>= 1) s += __shfl_down(s, off);
    if (lane == 0) ksq[wid] = -s * LOG2E / temp[0];
  }
}

// ---------------------------------------------------------------------------
// attn_rbf_kernel: round-0's verified dataflow, re-partitioned onto 8 waves
// (512 threads) for 4 waves/SIMD.  Same BM=64/BH=128, same kp/vp/ksq/P/OL
// layouts, bitwise-identical arithmetic:
//   QK^T: wave w = (rh = w>>2, kq = w&3) computes key tiles kt in
//         {2kq, 2kq+1} x row tiles rt in {2rh, 2rh+1} (16 MFMAs; xf 32 VGPR).
//   PV:   wave w owns C-tile ct = w for w < 7 (16 MFMAs); wave 7 idle in PV.
// One barrier/iter, double-buffered P, same epilogue (each ct has a unique
// owner -> no partial combine needed).
// ---------------------------------------------------------------------------
__global__ __launch_bounds__(512, 4)
void attn_rbf_kernel(const float* __restrict__ x,
                     const unsigned short* __restrict__ kp,
                     const float* __restrict__ ksq,
                     const unsigned short* __restrict__ vp,
                     float* __restrict__ out) {
  __shared__ __align__(16) char smem[2 * P_BYTES];  // 34816 B; epilogue OL aliases front
  float* OL = (float*)smem;
  float* rden = (float*)(smem + BM * OL_STRIDE * 4);  // 64 floats at +28928

  const int tid = threadIdx.x;
  const int w = tid >> 6;       // wave 0..7
  const int lane = tid & 63;
  const int n0 = lane & 15;
  const int q = lane >> 4;
  const int rh = w >> 2;        // row half 0/1 (rt in {2rh, 2rh+1})
  const int kq = w & 3;         // key quarter (kt in {2kq, 2kq+1})
  const int ct = w;             // PV C-tile (valid for w < 7)
  const bool has_ct = (w < 7);
  const int b = blockIdx.x;     // row block: rows [64b, 64b+64)

  // X B-fragments for this wave's 2 row tiles (same formula as round 0,
  // rt = 2rh + i): xf[i][c]
  short8 xf[2][4];
#pragma unroll
  for (int i = 0; i < 2; ++i)
#pragma unroll
    for (int c = 0; c < 4; ++c) {
      const float* s = x + (size_t)(b * 64 + (2 * rh + i) * 16 + n0) * D_DIM + c * 32 + q * 8;
      float4 lo = *(const float4*)s;
      float4 hi = *(const float4*)(s + 4);
      union { short8 v; unsigned int u[4]; } cv;
      cv.u[0] = pk2bf(lo.x, lo.y);
      cv.u[1] = pk2bf(lo.z, lo.w);
      cv.u[2] = pk2bf(hi.x, hi.y);
      cv.u[3] = pk2bf(hi.z, hi.w);
      xf[i][c] = cv.v;
    }

  floatx4 oacc[4];
#pragma unroll
  for (int rt = 0; rt < 4; ++rt) oacc[rt] = (floatx4){0.f, 0.f, 0.f, 0.f};

  for (int it = 0; it < H_KEYS / BH; ++it) {
    unsigned short* P = (unsigned short*)(smem + (it & 1) * P_BYTES);

    // ---- global prefetch (L2-resident streams) ----
    floatx4 ksq4[2];
#pragma unroll
    for (int kt = 0; kt < 2; ++kt)
      ksq4[kt] = *(const floatx4*)(ksq + it * BH + (2 * kq + kt) * 16 + q * 4);

    short8 vf[4];
    if (has_ct) {
#pragma unroll
      for (int c = 0; c < 4; ++c)
        vf[c] = *(const short8*)(vp + ((size_t)((it * 4 + c) * 7 + ct) * 64 + lane) * 8);
    }

    // ---- S^T = K . X^T, C initialized to -ksq (folded softmax bias) ----
#pragma unroll
    for (int kt = 0; kt < 2; ++kt) {
      const int ktg = 2 * kq + kt;   // global key tile 0..7 within iter
      short8 kf[4];
#pragma unroll
      for (int c = 0; c < 4; ++c)
        kf[c] = *(const short8*)(kp + ((size_t)((it * 8 + ktg) * 4 + c) * 64 + lane) * 8);
      floatx4 s[2];
#pragma unroll
      for (int i = 0; i < 2; ++i) s[i] = ksq4[kt];
#pragma unroll
      for (int c = 0; c < 4; ++c)
#pragma unroll
        for (int i = 0; i < 2; ++i)
          s[i] = __builtin_amdgcn_mfma_f32_16x16x32_bf16(kf[c], xf[i][c], s[i], 0, 0, 0);
      // exp2 + packed cvt: 4 keys -> one ds_write_b64
#pragma unroll
      for (int i = 0; i < 2; ++i) {
        uint2 pk;
        pk.x = pk2bf(__builtin_amdgcn_exp2f(s[i][0]), __builtin_amdgcn_exp2f(s[i][1]));
        pk.y = pk2bf(__builtin_amdgcn_exp2f(s[i][2]), __builtin_amdgcn_exp2f(s[i][3]));
        *(uint2*)(P + ((2 * rh + i) * 16 + n0) * P_STRIDE + ktg * 16 + q * 4) = pk;
      }
    }
    __syncthreads();  // single barrier: P complete; next iter writes the other buffer

    // ---- O += P . V (wave w owns C-tile ct, all 64 rows) ----
    if (has_ct) {
#pragma unroll
      for (int c = 0; c < 4; ++c) {
        short8 pf[4];
#pragma unroll
        for (int rt = 0; rt < 4; ++rt)
          pf[rt] = *(const short8*)(P + (rt * 16 + n0) * P_STRIDE + c * 32 + q * 8);
#pragma unroll
        for (int rt = 0; rt < 4; ++rt)
          oacc[rt] = __builtin_amdgcn_mfma_f32_16x16x32_bf16(pf[rt], vf[c], oacc[rt], 0, 0, 0);
      }
    }
  }
  __syncthreads();  // all waves done reading P before OL overlays it

  // ---- epilogue: O tiles -> LDS fp32, per-row reciprocal, coalesced store ----
  if (has_ct) {
#pragma unroll
    for (int rt = 0; rt < 4; ++rt)
#pragma unroll
      for (int i = 0; i < 4; ++i)
        OL[(rt * 16 + q * 4 + i) * OL_STRIDE + ct * 16 + n0] = oacc[rt][i];
  }
  __syncthreads();
  if (tid < BM) rden[tid] = 1.0f / OL[tid * OL_STRIDE + 100];
  __syncthreads();

  float* outb = out + (size_t)b * (BM * C_COLS);
  for (int idx = tid; idx < BM * C_COLS; idx += 512) {
    int n = idx / C_COLS;
    int cc = idx - n * C_COLS;
    outb[idx] = OL[n * OL_STRIDE + cc] * rden[n];
  }
}

extern "C" void kernel_launch(void* const* d_in, const int* in_sizes, int n_in,
                              void* d_out, int out_size, void* d_ws, size_t ws_size,
                              hipStream_t stream) {
  (void)in_sizes; (void)n_in; (void)out_size; (void)ws_size;
  const float* x      = (const float*)d_in[0];
  const float* keys   = (const float*)d_in[1];
  const float* values = (const float*)d_in[2];
  const float* temp   = (const float*)d_in[3];
  float* out = (float*)d_out;

  char* ws = (char*)d_ws;
  unsigned short* kp  = (unsigned short*)(ws);             // 8192*128*2 = 2097152 B
  unsigned short* vp  = (unsigned short*)(ws + 2097152);   // 8192*112*2 = 1835008 B
  float*          ksq = (float*)(ws + 3932160);            // 8192*4     = 32768 B

  hipLaunchKernelGGL(pack_all,        dim3(2816), dim3(256), 0, stream,
                     keys, values, temp, kp, vp, ksq);
  hipLaunchKernelGGL(attn_rbf_kernel, dim3(512),  dim3(512), 0, stream, x, kp, ksq, vp, out);
}

// Round 8
// 221.152 us; speedup vs baseline: 1.3757x; 1.3757x over previous
//
#include <hip/hip_runtime.h>
#include <hip/hip_bf16.h>

typedef __attribute__((ext_vector_type(8))) short short8;
typedef __attribute__((ext_vector_type(4))) float floatx4;

#define N_ROWS 32768
#define D_DIM  128
#define H_KEYS 8192
#define C_COLS 100
#define BM     64
#define BH     128
#define P_STRIDE  136   // ushorts per P row (272 B, 16B-aligned rows)
#define P_BYTES   (BM * P_STRIDE * 2)   // 17408 B per buffer
#define OL_STRIDE 113   // floats per OL row (odd -> conflict-free epilogue)
#define LOG2E 1.4426950408889634f

__device__ __forceinline__ unsigned short f2bf(float f) {
  union { float f; unsigned int u; } v; v.f = f;
  unsigned int r = v.u + 0x7fffu + ((v.u >> 16) & 1u);  // RNE
  return (unsigned short)(r >> 16);
}

// v_cvt_pk_bf16_f32: two fp32 -> packed bf16 (a in low 16, b in high 16)
__device__ __forceinline__ unsigned int pk2bf(float a, float b) {
  union { __hip_bfloat162 h; unsigned int u; } c;
  c.h = __float22bfloat162_rn(float2{a, b});
  return c.u;
}

// ---------------------------------------------------------------------------
// pack_all: single-launch fusion of the three preprocessing passes
// (verbatim round-0 logic, harness-verified twice) + zeroing of the
// denominator-accumulation buffer.
//   blocks [0,512):    pack_k — K fp32 -> MFMA A-frag order, scaled 2*log2e/T
//   blocks [512,768):  pack_v — V -> PV B-frag order, 112 cols, ones at 100
//   blocks [768,2816): ksq    — ksq[h] = -|k_h|^2 * log2e / T (1 wave/key)
//                      + den[0..32768) = 0
// ---------------------------------------------------------------------------
__global__ __launch_bounds__(256) void pack_all(const float* __restrict__ keys,
                                                const float* __restrict__ values,
                                                const float* __restrict__ temp,
                                                unsigned short* __restrict__ kp,
                                                unsigned short* __restrict__ vp,
                                                float* __restrict__ ksq,
                                                float* __restrict__ den) {
  const int bid = blockIdx.x;
  if (bid < 512) {
    int gid = bid * 256 + threadIdx.x;
    int lane = gid & 63;
    int c = (gid >> 6) & 3;
    int rt = gid >> 8;
    float scale = 2.0f * LOG2E / temp[0];
    int row = rt * 16 + (lane & 15);
    int d0 = c * 32 + (lane >> 4) * 8;
    const float* s = keys + (size_t)row * D_DIM + d0;
    short8 o;
#pragma unroll
    for (int j = 0; j < 8; ++j) o[j] = (short)f2bf(s[j] * scale);
    *(short8*)(kp + (size_t)gid * 8) = o;
  } else if (bid < 768) {
    __shared__ float vt[32 * 113];
    int g = bid - 512;
    int tid = threadIdx.x;
    for (int idx = tid; idx < 32 * 112; idx += 256) {
      int k = idx / 112, col = idx - k * 112;
      float val;
      if (col < C_COLS) val = values[(size_t)(g * 32 + k) * C_COLS + col];
      else val = (col == C_COLS) ? 1.0f : 0.0f;
      vt[k * 113 + col] = val;
    }
    __syncthreads();
    for (int u = tid; u < 7 * 64; u += 256) {
      int ct = u >> 6, l = u & 63;
      int n0 = l & 15, q = l >> 4;
      short8 o;
#pragma unroll
      for (int j = 0; j < 8; ++j) o[j] = (short)f2bf(vt[(q * 8 + j) * 113 + ct * 16 + n0]);
      *(short8*)(vp + ((size_t)(g * 7 + ct) * 64 + l) * 8) = o;
    }
  } else {
    int z = (bid - 768) * 256 + threadIdx.x;
    if (z < N_ROWS) den[z] = 0.0f;     // zero the denominator accumulator
    int wid = z >> 6;                  // key index
    int lane = threadIdx.x & 63;
    const float2* row = (const float2*)(keys + (size_t)wid * D_DIM);
    float2 v = row[lane];
    float s = v.x * v.x + v.y * v.y;
#pragma unroll
    for (int off = 32; off > 0; off >>= 1) s += __shfl_down(s, off);
    if (lane == 0) ksq[wid] = -s * LOG2E / temp[0];
  }
}

// ---------------------------------------------------------------------------
// attn_rbf_kernel: VERBATIM round-0 body (VGPR~108, prefetch schedule intact),
// with the key range split across 2 blocks per row-block:
//   blockIdx.x = 2*b + kh ; block processes keys [4096*kh, 4096*(kh+1)).
// Partial O (unnormalized, linear in keys) is atomicAdd'ed into out
// (pre-zeroed by the harness); partial denominator into den[].
// Exactly 2 fp32 contributions per cell -> order-independent sum.
// Grid 1024 -> 4 blocks/CU -> 4 waves/SIMD (vs round-0's 2), same per-wave ILP.
// ---------------------------------------------------------------------------
__global__ __launch_bounds__(256, 2)
void attn_rbf_kernel(const float* __restrict__ x,
                     const unsigned short* __restrict__ kp,
                     const float* __restrict__ ksq,
                     const unsigned short* __restrict__ vp,
                     float* __restrict__ out,
                     float* __restrict__ den) {
  __shared__ __align__(16) char smem[2 * P_BYTES];  // 34816 B; epilogue OL aliases front
  float* OL = (float*)smem;

  const int tid = threadIdx.x;
  const int w = tid >> 6;       // wave 0..3
  const int lane = tid & 63;
  const int n0 = lane & 15;
  const int q = lane >> 4;
  const int b  = blockIdx.x >> 1;   // row block: rows [64b, 64b+64)
  const int kh = blockIdx.x & 1;    // key half: iterations [32kh, 32kh+32)

  // Load x rows for this block directly (fp32 row-major), convert to B-fragments.
  short8 xf[4][4];
#pragma unroll
  for (int rt = 0; rt < 4; ++rt)
#pragma unroll
    for (int c = 0; c < 4; ++c) {
      const float* s = x + (size_t)(b * 64 + rt * 16 + n0) * D_DIM + c * 32 + q * 8;
      float4 lo = *(const float4*)s;
      float4 hi = *(const float4*)(s + 4);
      union { short8 v; unsigned int u[4]; } cv;
      cv.u[0] = pk2bf(lo.x, lo.y);
      cv.u[1] = pk2bf(lo.z, lo.w);
      cv.u[2] = pk2bf(hi.x, hi.y);
      cv.u[3] = pk2bf(hi.z, hi.w);
      xf[rt][c] = cv.v;
    }

  floatx4 oacc[4][2];
#pragma unroll
  for (int rt = 0; rt < 4; ++rt)
#pragma unroll
    for (int u = 0; u < 2; ++u)
      oacc[rt][u] = (floatx4){0.f, 0.f, 0.f, 0.f};

  const int nct = (w < 3) ? 2 : 1;  // waves own C-tiles {0,1},{2,3},{4,5},{6}
  const int ct0 = w * 2;

  const int it0 = kh * 32;
  for (int it = it0; it < it0 + 32; ++it) {
    unsigned short* P = (unsigned short*)(smem + (it & 1) * P_BYTES);

    // ---- global prefetch (L2-resident streams) ----
    short8 kf[2][4];
#pragma unroll
    for (int kt = 0; kt < 2; ++kt)
#pragma unroll
      for (int c = 0; c < 4; ++c)
        kf[kt][c] = *(const short8*)(kp + ((size_t)((it * 8 + w * 2 + kt) * 4 + c) * 64 + lane) * 8);

    floatx4 ksq4[2];
#pragma unroll
    for (int kt = 0; kt < 2; ++kt)
      ksq4[kt] = *(const floatx4*)(ksq + it * BH + w * 32 + kt * 16 + q * 4);

    short8 vf[4][2];
#pragma unroll
    for (int c = 0; c < 4; ++c)
#pragma unroll
      for (int u = 0; u < 2; ++u)
        if (u < nct)
          vf[c][u] = *(const short8*)(vp + ((size_t)((it * 4 + c) * 7 + (ct0 + u)) * 64 + lane) * 8);

    // ---- S^T = K . X^T, C initialized to -ksq (folded softmax bias) ----
#pragma unroll
    for (int kt = 0; kt < 2; ++kt) {
      floatx4 s[4];
#pragma unroll
      for (int rt = 0; rt < 4; ++rt) s[rt] = ksq4[kt];
#pragma unroll
      for (int c = 0; c < 4; ++c)
#pragma unroll
        for (int rt = 0; rt < 4; ++rt)
          s[rt] = __builtin_amdgcn_mfma_f32_16x16x32_bf16(kf[kt][c], xf[rt][c], s[rt], 0, 0, 0);
      // exp2 + packed cvt: 4 keys -> one ds_write_b64
#pragma unroll
      for (int rt = 0; rt < 4; ++rt) {
        uint2 pk;
        pk.x = pk2bf(__builtin_amdgcn_exp2f(s[rt][0]), __builtin_amdgcn_exp2f(s[rt][1]));
        pk.y = pk2bf(__builtin_amdgcn_exp2f(s[rt][2]), __builtin_amdgcn_exp2f(s[rt][3]));
        *(uint2*)(P + (rt * 16 + n0) * P_STRIDE + w * 32 + kt * 16 + q * 4) = pk;
      }
    }
    __syncthreads();  // single barrier: P complete; next iter writes the other buffer

    // ---- O += P . V (wave w owns its C-tiles, all 64 rows) ----
#pragma unroll
    for (int c = 0; c < 4; ++c) {
      short8 pf[4];
#pragma unroll
      for (int rt = 0; rt < 4; ++rt)
        pf[rt] = *(const short8*)(P + (rt * 16 + n0) * P_STRIDE + c * 32 + q * 8);
#pragma unroll
      for (int u = 0; u < 2; ++u)
        if (u < nct)
#pragma unroll
          for (int rt = 0; rt < 4; ++rt)
            oacc[rt][u] = __builtin_amdgcn_mfma_f32_16x16x32_bf16(pf[rt], vf[c][u], oacc[rt][u], 0, 0, 0);
    }
  }
  __syncthreads();  // all waves done reading P before OL overlays it

  // ---- epilogue: O tiles -> LDS fp32, then atomicAdd partials ----
#pragma unroll
  for (int rt = 0; rt < 4; ++rt)
#pragma unroll
    for (int u = 0; u < 2; ++u)
      if (u < nct)
#pragma unroll
        for (int i = 0; i < 4; ++i)
          OL[(rt * 16 + q * 4 + i) * OL_STRIDE + (ct0 + u) * 16 + n0] = oacc[rt][u][i];
  __syncthreads();
  if (tid < BM) atomicAdd(&den[b * BM + tid], OL[tid * OL_STRIDE + 100]);

  float* outb = out + (size_t)b * (BM * C_COLS);
  for (int idx = tid; idx < BM * C_COLS; idx += 256) {
    int n = idx / C_COLS;
    int cc = idx - n * C_COLS;
    atomicAdd(&outb[idx], OL[n * OL_STRIDE + cc]);
  }
}

// ---------------------------------------------------------------------------
// norm_kernel: out[row][:] *= 1/den[row].  512 blocks x 256 threads,
// 64 rows/block; reciprocals staged in LDS.
// ---------------------------------------------------------------------------
__global__ __launch_bounds__(256) void norm_kernel(float* __restrict__ out,
                                                   const float* __restrict__ den) {
  __shared__ float rl[BM];
  const int b = blockIdx.x;
  const int tid = threadIdx.x;
  if (tid < BM) rl[tid] = 1.0f / den[b * BM + tid];
  __syncthreads();
  float* outb = out + (size_t)b * (BM * C_COLS);
  for (int idx = tid; idx < BM * C_COLS; idx += 256) {
    int n = idx / C_COLS;
    outb[idx] *= rl[n];
  }
}

extern "C" void kernel_launch(void* const* d_in, const int* in_sizes, int n_in,
                              void* d_out, int out_size, void* d_ws, size_t ws_size,
                              hipStream_t stream) {
  (void)in_sizes; (void)n_in; (void)out_size; (void)ws_size;
  const float* x      = (const float*)d_in[0];
  const float* keys   = (const float*)d_in[1];
  const float* values = (const float*)d_in[2];
  const float* temp   = (const float*)d_in[3];
  float* out = (float*)d_out;

  char* ws = (char*)d_ws;
  unsigned short* kp  = (unsigned short*)(ws);             // 2,097,152 B
  unsigned short* vp  = (unsigned short*)(ws + 2097152);   // 1,835,008 B
  float*          ksq = (float*)(ws + 3932160);            //    32,768 B
  float*          den = (float*)(ws + 3964928);            //   131,072 B (tot 4,096,000)

  hipLaunchKernelGGL(pack_all,        dim3(2816), dim3(256), 0, stream,
                     keys, values, temp, kp, vp, ksq, den);
  hipLaunchKernelGGL(attn_rbf_kernel, dim3(1024), dim3(256), 0, stream,
                     x, kp, ksq, vp, out, den);
  hipLaunchKernelGGL(norm_kernel,     dim3(512),  dim3(256), 0, stream, out, den);
}